// Round 11
// baseline (35.415 us; speedup 1.0000x reference)
//
#include <hip/hip_runtime.h>

// Problem constants (from reference)
#define NRB 512
#define NTK 1024
#define DD  64
#define GHH 128

// Dead dataflow: tgt = edge_index[1]+512 in [512,1536) but robot_msgs =
// agg[:512] -> all-zero => edge MLP + segment_sum dead. lrelu(x) =
// 0.55x + 0.45|x| factors score into a[n] + c[m] + sum_h wb[h]*|HR+HTB|.
//
// R2: grid.sync ~60us -> kernel boundaries. R3: 256 VGPR latency-bound.
// R4: transpose for coalescing. R5: reg-array staging spills. R6-R8: score
// ~floor (HTBt4 L1 stream ~4us). R9: b128 prep. R10: fused robot-MLP via
// 150KB LDS staging regressed (+2us serial). R11: robot MLP wave-per-neuron,
// weights DIRECT from global (coalesced 256B/wave rows, L2-hot), shfl-xor
// reduce; LDS ~6KB; task prep unchanged (R10-validated).

// Workspace layout (floats):
//   HTBt4 [32][1024][4]  @ 0        (h-interleaved transpose, incl bm1)
//   c     [1024]         @ 131072   (incl bm2)

// ---------------------------------------------------------------------------
// Kernel 1: task prep. 128 blocks x 256 threads; block b -> tasks 8b..8b+7.
// HTBt4[h4][m] = (x_task@Wm1[:,128:].T + bm1) packed 4-h per f4; cv[m].
// ---------------------------------------------------------------------------
__global__ __launch_bounds__(256) void task_prep_kernel(
    const float* __restrict__ xt,
    const float* __restrict__ Wm1, const float* __restrict__ bm1,
    const float* __restrict__ Wm2, const float* __restrict__ bm2,
    float* __restrict__ HTBt4, float* __restrict__ cv)
{
    const int t = threadIdx.x;   // 0..255
    const int b = blockIdx.x;    // 0..127
    const int i = t & 127;       // output neuron
    const int g = t >> 7;        // row-group 0/1

    __shared__ float lds_w[128 * 132];
    __shared__ float xs[8 * 64];
    __shared__ float sT[8 * 132];
    __shared__ float sR[8 * 132];

    float4* Lw = reinterpret_cast<float4*>(lds_w);

    const int t0 = b * 8;
    xs[t]       = xt[t0 * DD + t];
    xs[256 + t] = xt[t0 * DD + 256 + t];

    // stage Wt = Wm1[:,128:192]: 2048 f4
    {
        const float4* W = reinterpret_cast<const float4*>(Wm1);
        #pragma unroll
        for (int j = 0; j < 8; ++j) {
            const int e = t + 256 * j;
            const int row = e >> 4, c4 = e & 15;
            Lw[row * 33 + c4] = W[row * 48 + 32 + c4];
        }
    }
    __syncthreads();

    // rows 4g..4g+3: htb = x_task @ Wt^T + bm1
    {
        const float bb  = bm1[i];
        const float wm2 = Wm2[i];
        float a0 = bb, a1 = bb, a2 = bb, a3 = bb;
        const float4* w4 = Lw + i * 33;
        const float4* x0 = reinterpret_cast<const float4*>(xs + (4*g)*64);
        const float4* x1 = reinterpret_cast<const float4*>(xs + (4*g+1)*64);
        const float4* x2 = reinterpret_cast<const float4*>(xs + (4*g+2)*64);
        const float4* x3 = reinterpret_cast<const float4*>(xs + (4*g+3)*64);
        #pragma unroll
        for (int k = 0; k < 16; ++k) {
            const float4 w = w4[k];
            const float4 p0 = x0[k], p1 = x1[k], p2 = x2[k], p3 = x3[k];
            a0 = fmaf(w.x, p0.x, a0); a1 = fmaf(w.x, p1.x, a1);
            a2 = fmaf(w.x, p2.x, a2); a3 = fmaf(w.x, p3.x, a3);
            a0 = fmaf(w.y, p0.y, a0); a1 = fmaf(w.y, p1.y, a1);
            a2 = fmaf(w.y, p2.y, a2); a3 = fmaf(w.y, p3.y, a3);
            a0 = fmaf(w.z, p0.z, a0); a1 = fmaf(w.z, p1.z, a1);
            a2 = fmaf(w.z, p2.z, a2); a3 = fmaf(w.z, p3.z, a3);
            a0 = fmaf(w.w, p0.w, a0); a1 = fmaf(w.w, p1.w, a1);
            a2 = fmaf(w.w, p2.w, a2); a3 = fmaf(w.w, p3.w, a3);
        }
        sT[(4*g)*132 + i]   = a0;  sR[(4*g)*132 + i]   = wm2 * a0;
        sT[(4*g+1)*132 + i] = a1;  sR[(4*g+1)*132 + i] = wm2 * a1;
        sT[(4*g+2)*132 + i] = a2;  sR[(4*g+2)*132 + i] = wm2 * a2;
        sT[(4*g+3)*132 + i] = a3;  sR[(4*g+3)*132 + i] = wm2 * a3;
    }
    __syncthreads();

    // interleaved transposed write: HTBt4[h4][t0+tk] = htb[tk][4h4..4h4+3]
    {
        const int h4 = t >> 3, tk = t & 7;
        float4 v;
        v.x = sT[tk*132 + 4*h4 + 0];
        v.y = sT[tk*132 + 4*h4 + 1];
        v.z = sT[tk*132 + 4*h4 + 2];
        v.w = sT[tk*132 + 4*h4 + 3];
        reinterpret_cast<float4*>(HTBt4)[h4 * NTK + t0 + tk] = v;
    }

    // c[m] = 0.55 * sum_i sR[m][i] + bm2;  half-wave per task
    {
        const int row = t >> 5, c = t & 31;
        float s = sR[row*132 + c]      + sR[row*132 + c + 32]
                + sR[row*132 + c + 64] + sR[row*132 + c + 96];
        #pragma unroll
        for (int off = 16; off >= 1; off >>= 1)
            s += __shfl_xor(s, off, 32);
        if (c == 0) cv[t0 + row] = 0.55f * s + bm2[0];
    }
}

// ---------------------------------------------------------------------------
// Kernel 2: robot MLP + score + softmax. 256 blocks x 1024 threads.
// Block b owns robot rows n0=2b,2b+1 and all 1024 m (thread tid = m).
// Phase A (wave-per-neuron): wave wv handles neuron i = 16p+wv; 64 lanes
// read W[i][k] coalesced from GLOBAL (L2-hot), multiply LDS-resident x/h,
// shfl_xor butterfly reduce. No weight staging; LDS ~6 KB.
// Phase B: 32 iters of {1 coalesced dwordx4 HTBt4 + 3 LDS f4 broadcasts +
// 16 VALU}; block softmax; coalesced store.
// ---------------------------------------------------------------------------
__global__ __launch_bounds__(1024) void robot_score_softmax_kernel(
    const float* __restrict__ xr,
    const float* __restrict__ Wv1, const float* __restrict__ bv1,
    const float* __restrict__ Wv2, const float* __restrict__ bv2,
    const float* __restrict__ Wm1, const float* __restrict__ Wm2,
    const float* __restrict__ HTBt4, const float* __restrict__ cv,
    float* __restrict__ out)
{
    const int b   = blockIdx.x;     // 0..255
    const int tid = threadIdx.x;    // 0..1023 == m
    const int n0  = b * 2;
    const int wv  = tid >> 6;       // wave 0..15
    const int ln  = tid & 63;

    __shared__ __align__(16) float xs[2][64];
    __shared__ __align__(16) float h1[2][128];
    __shared__ __align__(16) float hh[2][128];
    __shared__ __align__(16) float s_hr[2 * 128];
    __shared__ __align__(16) float s_pr[2 * 128];
    __shared__ __align__(16) float s_wb[128];
    __shared__ float s_av[2], s_pp[2][2];

    // load cv early (independent; hides under phase A)
    const float cm = cv[tid];

    // ---------------- Phase A: robot MLP for rows n0, n0+1 ----------------
    if (tid < 128) {
        xs[tid >> 6][tid & 63] = xr[n0 * DD + tid];
        s_wb[tid] = 0.45f * Wm2[tid];
    }
    __syncthreads();

    // layer 1: h1[r][i] = lrelu(bv1[i] + sum_k x[r][k] * Wv1[i][128+k])
    {
        const float x0 = xs[0][ln];
        const float x1 = xs[1][ln];
        #pragma unroll
        for (int p = 0; p < 8; ++p) {
            const int i = p * 16 + wv;
            const float w = Wv1[i * 192 + 128 + ln];   // coalesced row read
            float p0 = w * x0;
            float p1 = w * x1;
            #pragma unroll
            for (int off = 32; off >= 1; off >>= 1) {
                p0 += __shfl_xor(p0, off, 64);
                p1 += __shfl_xor(p1, off, 64);
            }
            if (ln == 0) {
                const float bb = bv1[i];
                float a0 = p0 + bb, a1 = p1 + bb;
                h1[0][i] = (a0 >= 0.f) ? a0 : 0.1f * a0;
                h1[1][i] = (a1 >= 0.f) ? a1 : 0.1f * a1;
            }
        }
    }
    __syncthreads();

    // layer 2: hh[r][i] = bv2[i] + sum_k h1[r][k] * Wv2[i][k]
    {
        const float ha0 = h1[0][ln], hb0 = h1[0][64 + ln];
        const float ha1 = h1[1][ln], hb1 = h1[1][64 + ln];
        #pragma unroll
        for (int p = 0; p < 8; ++p) {
            const int i = p * 16 + wv;
            const float wa = Wv2[i * 128 + ln];
            const float wb = Wv2[i * 128 + 64 + ln];
            float p0 = fmaf(wa, ha0, wb * hb0);
            float p1 = fmaf(wa, ha1, wb * hb1);
            #pragma unroll
            for (int off = 32; off >= 1; off >>= 1) {
                p0 += __shfl_xor(p0, off, 64);
                p1 += __shfl_xor(p1, off, 64);
            }
            if (ln == 0) {
                const float bb = bv2[i];
                hh[0][i] = p0 + bb;
                hh[1][i] = p1 + bb;
            }
        }
    }
    __syncthreads();

    // layer 3: hr[r][i] = sum_k hh[r][k] * Wm1[i][k];  also Wm2[i]*hr
    {
        const float ha0 = hh[0][ln], hb0 = hh[0][64 + ln];
        const float ha1 = hh[1][ln], hb1 = hh[1][64 + ln];
        #pragma unroll
        for (int p = 0; p < 8; ++p) {
            const int i = p * 16 + wv;
            const float wa = Wm1[i * 192 + ln];
            const float wb = Wm1[i * 192 + 64 + ln];
            float p0 = fmaf(wa, ha0, wb * hb0);
            float p1 = fmaf(wa, ha1, wb * hb1);
            #pragma unroll
            for (int off = 32; off >= 1; off >>= 1) {
                p0 += __shfl_xor(p0, off, 64);
                p1 += __shfl_xor(p1, off, 64);
            }
            if (ln == 0) {
                const float wm2 = Wm2[i];
                s_hr[i]       = p0;  s_pr[i]       = wm2 * p0;
                s_hr[128 + i] = p1;  s_pr[128 + i] = wm2 * p1;
            }
        }
    }
    __syncthreads();

    // a[n] = 0.55 * sum_i s_pr[n][i]   (4 waves: r = tid>>7, 2 waves each)
    if (tid < 256) {
        const int r = tid >> 7, c = tid & 127;
        float s = s_pr[r * 128 + c];
        #pragma unroll
        for (int off = 32; off >= 1; off >>= 1)
            s += __shfl_xor(s, off, 64);
        if ((c & 63) == 0) s_pp[r][c >> 6] = s;
    }
    __syncthreads();
    if (tid < 2) s_av[tid] = 0.55f * (s_pp[tid][0] + s_pp[tid][1]);
    __syncthreads();

    // ---------------- Phase B: score + softmax ----------------
    const float4* tb  = reinterpret_cast<const float4*>(HTBt4) + tid;
    const float4* hrA = reinterpret_cast<const float4*>(s_hr);
    const float4* hrB = reinterpret_cast<const float4*>(s_hr + 128);
    const float4* wb4 = reinterpret_cast<const float4*>(s_wb);

    float acc0 = 0.f, acc1 = 0.f;

    #pragma unroll 4
    for (int h4 = 0; h4 < 32; ++h4) {
        const float4 v  = tb[h4 << 10];     // coalesced dwordx4
        const float4 w  = wb4[h4];          // LDS broadcast
        const float4 r0 = hrA[h4];
        const float4 r1 = hrB[h4];
        acc0 = fmaf(w.x, fabsf(r0.x + v.x), acc0);
        acc1 = fmaf(w.x, fabsf(r1.x + v.x), acc1);
        acc0 = fmaf(w.y, fabsf(r0.y + v.y), acc0);
        acc1 = fmaf(w.y, fabsf(r1.y + v.y), acc1);
        acc0 = fmaf(w.z, fabsf(r0.z + v.z), acc0);
        acc1 = fmaf(w.z, fabsf(r1.z + v.z), acc1);
        acc0 = fmaf(w.w, fabsf(r0.w + v.w), acc0);
        acc1 = fmaf(w.w, fabsf(r1.w + v.w), acc1);
    }

    float sc[2];
    sc[0] = acc0 + s_av[0] + cm;
    sc[1] = acc1 + s_av[1] + cm;

    // ---- block-local softmax over the 1024 columns, both rows ----
    __shared__ float rmax[2][16], rsum[2][16];
    const int lane = ln;

    #pragma unroll
    for (int n = 0; n < 2; ++n) {
        float mx = sc[n];
        #pragma unroll
        for (int off = 32; off >= 1; off >>= 1)
            mx = fmaxf(mx, __shfl_xor(mx, off, 64));
        if (lane == 0) rmax[n][wv] = mx;
    }
    __syncthreads();

    float ex[2];
    #pragma unroll
    for (int n = 0; n < 2; ++n) {
        float mx = rmax[n][0];
        #pragma unroll
        for (int k = 1; k < 16; ++k) mx = fmaxf(mx, rmax[n][k]);
        float e = expf(sc[n] - mx);
        ex[n] = e;
        float s = e;
        #pragma unroll
        for (int off = 32; off >= 1; off >>= 1) s += __shfl_xor(s, off, 64);
        if (lane == 0) rsum[n][wv] = s;
    }
    __syncthreads();

    #pragma unroll
    for (int n = 0; n < 2; ++n) {
        float s = rsum[n][0];
        #pragma unroll
        for (int k = 1; k < 16; ++k) s += rsum[n][k];
        out[(n0 + n) * NTK + tid] = ex[n] * (1.0f / s);
    }
}

extern "C" void kernel_launch(void* const* d_in, const int* in_sizes, int n_in,
                              void* d_out, int out_size, void* d_ws, size_t ws_size,
                              hipStream_t stream)
{
    const float* xr  = (const float*)d_in[0];
    const float* xt  = (const float*)d_in[1];
    // d_in[2]=edge_index, [3]=edge_attr, [4..7]=We1,be1,We2,be2 : provably dead
    const float* Wv1 = (const float*)d_in[8];
    const float* bv1 = (const float*)d_in[9];
    const float* Wv2 = (const float*)d_in[10];
    const float* bv2 = (const float*)d_in[11];
    const float* Wm1 = (const float*)d_in[12];
    const float* bm1 = (const float*)d_in[13];
    const float* Wm2 = (const float*)d_in[14];
    const float* bm2 = (const float*)d_in[15];

    float* ws    = (float*)d_ws;
    float* HTBt4 = ws;
    float* cv    = ws + 131072;
    float* out   = (float*)d_out;

    hipLaunchKernelGGL(task_prep_kernel, dim3(128), dim3(256), 0, stream,
                       xt, Wm1, bm1, Wm2, bm2, HTBt4, cv);
    hipLaunchKernelGGL(robot_score_softmax_kernel, dim3(256), dim3(1024), 0, stream,
                       xr, Wv1, bv1, Wv2, bv2, Wm1, Wm2, HTBt4, cv, out);
}

// Round 12
// 24.039 us; speedup vs baseline: 1.4732x; 1.4732x over previous
//
#include <hip/hip_runtime.h>

// Problem constants (from reference)
#define NRB 512
#define NTK 1024
#define DD  64
#define GHH 128

// Dead dataflow: tgt = edge_index[1]+512 in [512,1536) but robot_msgs =
// agg[:512] -> all-zero => edge MLP + segment_sum dead. lrelu(x) =
// 0.55x + 0.45|x| factors score into a[n] + c[m] + sum_h wb[h]*|hr+htb|.
//
// R2: grid.sync ~60us. R3: 256 VGPR latency-bound. R4: transpose for
// coalescing. R5: reg-array staging spills. R9 (best, 22.58): b128 prep +
// f4 score. R10/R11: phase-A fusion attempts regressed (LDS re-stage +2us;
// shfl-MLP +11us). R12: wb-sign trick: prep pre-scales hr,htb by SIGNED wb
// and stably partitions h by sign(wb) (permutation, legal under sum_h).
// Score: add-loop |r+v| for positive h, subtract-loop for negative, one
// mixed boundary group with reg signs from nP. Aux reads 3->2 per iter,
// wb read eliminated -> score is pure L1-stream-bound (~3.4us floor).

// Workspace layout (floats):
//   HTB2t4 [32][1024][4] @ 0       (perm'd h, wb-scaled, incl bm1)
//   cv     [1024]        @ 131072  (incl bm2)
//   HR2    [512][128]    @ 132096  (perm'd h, wb-scaled)
//   av     [512]         @ 197632
//   nPf    [1]           @ 198144  (count of wb>0, as float)

// ---------------------------------------------------------------------------
// Kernel A: prep. 256 blocks x 256 threads (R9 structure + perm + scaling).
// Blocks 0..127: robot path, 4 robots -> HR2 rows + a[n].
// Blocks 128..255: task path, 8 tasks -> HTB2t4 + c[m]; block 128 nPf.
// ---------------------------------------------------------------------------
__global__ __launch_bounds__(256) void prep_kernel(
    const float* __restrict__ xr, const float* __restrict__ xt,
    const float* __restrict__ Wv1, const float* __restrict__ bv1,
    const float* __restrict__ Wv2, const float* __restrict__ bv2,
    const float* __restrict__ Wm1, const float* __restrict__ bm1,
    const float* __restrict__ Wm2, const float* __restrict__ bm2,
    float* __restrict__ HR2, float* __restrict__ HTB2t4,
    float* __restrict__ av, float* __restrict__ cv, float* __restrict__ nPf)
{
    const int t = threadIdx.x;   // 0..255
    const int b = blockIdx.x;    // 0..255
    const int i = t & 127;       // output neuron
    const int g = t >> 7;        // row-group 0/1

    __shared__ float lds_w[128 * 132];   // row-major weights, stride 132
    __shared__ float xs[8 * 64];
    __shared__ float sA[4 * 132];
    __shared__ float sB[4 * 132];
    __shared__ float sT[8 * 132];
    __shared__ float sR[8 * 132];
    __shared__ unsigned long long smask[2];

    float4* Lw = reinterpret_cast<float4*>(lds_w);

    // ---- permutation preamble: stable partition of h by sign(Wm2) ----
    const float wm2 = Wm2[i];
    const float wbv = 0.45f * wm2;
    const bool  pos = wm2 > 0.f;
    {
        unsigned long long mb = __ballot(pos);
        if (t < 128 && (t & 63) == 0) smask[t >> 6] = mb;
    }
    // (ranks derived after the first __syncthreads below)

    if (b < 128) {
        // ================= robot path: rows r0..r0+3 =================
        const int r0 = b * 4;
        xs[t] = xr[r0 * DD + t];                     // 256 floats, coalesced

        // stage W1 = Wv1[:,128:192]: 2048 f4
        {
            const float4* W = reinterpret_cast<const float4*>(Wv1);
            #pragma unroll
            for (int j = 0; j < 8; ++j) {
                const int e = t + 256 * j;
                const int row = e >> 4, c4 = e & 15;
                Lw[row * 33 + c4] = W[row * 48 + 32 + c4];
            }
        }
        __syncthreads();

        // perm rank (masks now visible)
        const unsigned long long m0 = smask[0], m1 = smask[1];
        const int nP = __popcll(m0) + __popcll(m1);
        int rankP;
        if (i < 64) rankP = __popcll(m0 & ((1ULL << i) - 1));
        else        rankP = __popcll(m0) + __popcll(m1 & ((1ULL << (i - 64)) - 1));
        const int p = pos ? rankP : nP + (i - rankP);

        // phase 1: h1 = lrelu(x @ W1^T + bv1), rows 2g,2g+1
        {
            float a0 = bv1[i], a1 = a0;
            const float4* w4 = Lw + i * 33;
            const float4* x0 = reinterpret_cast<const float4*>(xs + (2*g)*64);
            const float4* x1 = reinterpret_cast<const float4*>(xs + (2*g+1)*64);
            #pragma unroll
            for (int k = 0; k < 16; ++k) {
                const float4 w = w4[k];
                const float4 pq = x0[k];
                const float4 qq = x1[k];
                a0 = fmaf(w.x, pq.x, a0); a1 = fmaf(w.x, qq.x, a1);
                a0 = fmaf(w.y, pq.y, a0); a1 = fmaf(w.y, qq.y, a1);
                a0 = fmaf(w.z, pq.z, a0); a1 = fmaf(w.z, qq.z, a1);
                a0 = fmaf(w.w, pq.w, a0); a1 = fmaf(w.w, qq.w, a1);
            }
            sA[(2*g)*132 + i]   = (a0 >= 0.f) ? a0 : 0.1f * a0;
            sA[(2*g+1)*132 + i] = (a1 >= 0.f) ? a1 : 0.1f * a1;
        }
        __syncthreads();

        // stage W2 = Wv2: 4096 f4
        {
            const float4* W = reinterpret_cast<const float4*>(Wv2);
            #pragma unroll
            for (int j = 0; j < 16; ++j) {
                const int e = t + 256 * j;
                const int row = e >> 5, c4 = e & 31;
                Lw[row * 33 + c4] = W[row * 32 + c4];
            }
        }
        __syncthreads();

        // phase 2: h = h1 @ W2^T + bv2
        {
            float a0 = bv2[i], a1 = a0;
            const float4* w4 = Lw + i * 33;
            const float4* h0 = reinterpret_cast<const float4*>(sA + (2*g)*132);
            const float4* h1 = reinterpret_cast<const float4*>(sA + (2*g+1)*132);
            #pragma unroll 8
            for (int k = 0; k < 32; ++k) {
                const float4 w = w4[k];
                const float4 pq = h0[k];
                const float4 qq = h1[k];
                a0 = fmaf(w.x, pq.x, a0); a1 = fmaf(w.x, qq.x, a1);
                a0 = fmaf(w.y, pq.y, a0); a1 = fmaf(w.y, qq.y, a1);
                a0 = fmaf(w.z, pq.z, a0); a1 = fmaf(w.z, qq.z, a1);
                a0 = fmaf(w.w, pq.w, a0); a1 = fmaf(w.w, qq.w, a1);
            }
            sB[(2*g)*132 + i]   = a0;
            sB[(2*g+1)*132 + i] = a1;
        }
        __syncthreads();

        // stage W3 = Wm1[:, :128]: 4096 f4
        {
            const float4* W = reinterpret_cast<const float4*>(Wm1);
            #pragma unroll
            for (int j = 0; j < 16; ++j) {
                const int e = t + 256 * j;
                const int row = e >> 5, c4 = e & 31;
                Lw[row * 33 + c4] = W[row * 48 + c4];
            }
        }
        __syncthreads();

        // phase 3: hr = h @ W3^T; permuted scaled write + a-partials
        {
            float a0 = 0.f, a1 = 0.f;
            const float4* w4 = Lw + i * 33;
            const float4* h0 = reinterpret_cast<const float4*>(sB + (2*g)*132);
            const float4* h1 = reinterpret_cast<const float4*>(sB + (2*g+1)*132);
            #pragma unroll 8
            for (int k = 0; k < 32; ++k) {
                const float4 w = w4[k];
                const float4 pq = h0[k];
                const float4 qq = h1[k];
                a0 = fmaf(w.x, pq.x, a0); a1 = fmaf(w.x, qq.x, a1);
                a0 = fmaf(w.y, pq.y, a0); a1 = fmaf(w.y, qq.y, a1);
                a0 = fmaf(w.z, pq.z, a0); a1 = fmaf(w.z, qq.z, a1);
                a0 = fmaf(w.w, pq.w, a0); a1 = fmaf(w.w, qq.w, a1);
            }
            HR2[(r0 + 2*g) * GHH + p]     = wbv * a0;   // 2-run scatter
            HR2[(r0 + 2*g + 1) * GHH + p] = wbv * a1;
            sR[(2*g)*132 + i]   = wm2 * a0;
            sR[(2*g+1)*132 + i] = wm2 * a1;
        }
        __syncthreads();

        // a[n] = 0.55 * sum_i sR[n][i];  one wave per row
        {
            const int row = t >> 6, c = t & 63;
            float s = sR[row*132 + c] + sR[row*132 + c + 64];
            #pragma unroll
            for (int off = 32; off >= 1; off >>= 1)
                s += __shfl_xor(s, off, 64);
            if (c == 0) av[r0 + row] = 0.55f * s;
        }
    } else {
        // ================= task path: tasks t0..t0+7 =================
        const int t0 = (b - 128) * 8;
        xs[t]       = xt[t0 * DD + t];
        xs[256 + t] = xt[t0 * DD + 256 + t];

        // stage Wt = Wm1[:,128:192]: 2048 f4
        {
            const float4* W = reinterpret_cast<const float4*>(Wm1);
            #pragma unroll
            for (int j = 0; j < 8; ++j) {
                const int e = t + 256 * j;
                const int row = e >> 4, c4 = e & 15;
                Lw[row * 33 + c4] = W[row * 48 + 32 + c4];
            }
        }
        __syncthreads();

        const unsigned long long m0 = smask[0], m1 = smask[1];
        const int nP = __popcll(m0) + __popcll(m1);
        int rankP;
        if (i < 64) rankP = __popcll(m0 & ((1ULL << i) - 1));
        else        rankP = __popcll(m0) + __popcll(m1 & ((1ULL << (i - 64)) - 1));
        const int p = pos ? rankP : nP + (i - rankP);

        // rows 4g..4g+3: htb = x_task @ Wt^T + bm1
        {
            const float bb = bm1[i];
            float a0 = bb, a1 = bb, a2 = bb, a3 = bb;
            const float4* w4 = Lw + i * 33;
            const float4* x0 = reinterpret_cast<const float4*>(xs + (4*g)*64);
            const float4* x1 = reinterpret_cast<const float4*>(xs + (4*g+1)*64);
            const float4* x2 = reinterpret_cast<const float4*>(xs + (4*g+2)*64);
            const float4* x3 = reinterpret_cast<const float4*>(xs + (4*g+3)*64);
            #pragma unroll
            for (int k = 0; k < 16; ++k) {
                const float4 w = w4[k];
                const float4 p0 = x0[k], p1 = x1[k], p2 = x2[k], p3 = x3[k];
                a0 = fmaf(w.x, p0.x, a0); a1 = fmaf(w.x, p1.x, a1);
                a2 = fmaf(w.x, p2.x, a2); a3 = fmaf(w.x, p3.x, a3);
                a0 = fmaf(w.y, p0.y, a0); a1 = fmaf(w.y, p1.y, a1);
                a2 = fmaf(w.y, p2.y, a2); a3 = fmaf(w.y, p3.y, a3);
                a0 = fmaf(w.z, p0.z, a0); a1 = fmaf(w.z, p1.z, a1);
                a2 = fmaf(w.z, p2.z, a2); a3 = fmaf(w.z, p3.z, a3);
                a0 = fmaf(w.w, p0.w, a0); a1 = fmaf(w.w, p1.w, a1);
                a2 = fmaf(w.w, p2.w, a2); a3 = fmaf(w.w, p3.w, a3);
            }
            // permuted + wb-scaled staging for HTB2; raw products for c[m]
            sT[(4*g)*132 + p]   = wbv * a0;  sR[(4*g)*132 + i]   = wm2 * a0;
            sT[(4*g+1)*132 + p] = wbv * a1;  sR[(4*g+1)*132 + i] = wm2 * a1;
            sT[(4*g+2)*132 + p] = wbv * a2;  sR[(4*g+2)*132 + i] = wm2 * a2;
            sT[(4*g+3)*132 + p] = wbv * a3;  sR[(4*g+3)*132 + i] = wm2 * a3;
        }
        __syncthreads();

        // interleaved transposed write: HTB2t4[h4][t0+tk] (already perm'd)
        {
            const int h4 = t >> 3, tk = t & 7;
            float4 v;
            v.x = sT[tk*132 + 4*h4 + 0];
            v.y = sT[tk*132 + 4*h4 + 1];
            v.z = sT[tk*132 + 4*h4 + 2];
            v.w = sT[tk*132 + 4*h4 + 3];
            reinterpret_cast<float4*>(HTB2t4)[h4 * NTK + t0 + tk] = v;
        }

        // c[m] = 0.55 * sum_i sR[m][i] + bm2
        {
            const int row = t >> 5, c = t & 31;
            float s = sR[row*132 + c]      + sR[row*132 + c + 32]
                    + sR[row*132 + c + 64] + sR[row*132 + c + 96];
            #pragma unroll
            for (int off = 16; off >= 1; off >>= 1)
                s += __shfl_xor(s, off, 32);
            if (c == 0) cv[t0 + row] = 0.55f * s + bm2[0];
        }
        if (b == 128 && t == 0) nPf[0] = (float)nP;
    }
}

// ---------------------------------------------------------------------------
// Kernel B: fused score + softmax. 256 blocks x 1024 threads.
// Block b owns rows n0=2b,2b+1; thread tid owns column m=tid.
// Sign-partitioned h: add-loop (h'<nP) / mixed boundary group / sub-loop.
// Per h4: 1 coalesced dwordx4 stream + 2 LDS b128 broadcasts; NO wb read.
// ---------------------------------------------------------------------------
__global__ __launch_bounds__(1024) void score_softmax_kernel(
    const float* __restrict__ HR2, const float* __restrict__ HTB2t4,
    const float* __restrict__ av, const float* __restrict__ cv,
    const float* __restrict__ nPf, float* __restrict__ out)
{
    const int b   = blockIdx.x;     // 0..255
    const int tid = threadIdx.x;    // 0..1023 == m
    const int n0  = b * 2;

    __shared__ float s_hr[2 * GHH];
    if (tid < 256) s_hr[tid] = HR2[n0 * GHH + tid];
    const float cm  = cv[tid];
    const float a0v = av[n0], a1v = av[n0 + 1];
    const int   nP  = (int)nPf[0];
    __syncthreads();

    const float4* tb  = reinterpret_cast<const float4*>(HTB2t4) + tid;
    const float4* hrA = reinterpret_cast<const float4*>(s_hr);
    const float4* hrB = reinterpret_cast<const float4*>(s_hr + GHH);

    float acc0 = 0.f, acc1 = 0.f;
    const int gs = nP >> 2;

    #pragma unroll 4
    for (int h4 = 0; h4 < gs; ++h4) {          // positive-wb groups
        const float4 v  = tb[h4 << 10];
        const float4 r0 = hrA[h4];
        const float4 r1 = hrB[h4];
        acc0 += fabsf(r0.x + v.x); acc1 += fabsf(r1.x + v.x);
        acc0 += fabsf(r0.y + v.y); acc1 += fabsf(r1.y + v.y);
        acc0 += fabsf(r0.z + v.z); acc1 += fabsf(r1.z + v.z);
        acc0 += fabsf(r0.w + v.w); acc1 += fabsf(r1.w + v.w);
    }

    if (gs < 32) {                             // mixed boundary group
        const int j = nP & 3;
        const float s0 = (0 < j) ? 1.f : -1.f;
        const float s1 = (1 < j) ? 1.f : -1.f;
        const float s2 = (2 < j) ? 1.f : -1.f;
        const float s3 = (3 < j) ? 1.f : -1.f;
        const float4 v  = tb[gs << 10];
        const float4 r0 = hrA[gs];
        const float4 r1 = hrB[gs];
        acc0 = fmaf(s0, fabsf(r0.x + v.x), acc0);
        acc1 = fmaf(s0, fabsf(r1.x + v.x), acc1);
        acc0 = fmaf(s1, fabsf(r0.y + v.y), acc0);
        acc1 = fmaf(s1, fabsf(r1.y + v.y), acc1);
        acc0 = fmaf(s2, fabsf(r0.z + v.z), acc0);
        acc1 = fmaf(s2, fabsf(r1.z + v.z), acc1);
        acc0 = fmaf(s3, fabsf(r0.w + v.w), acc0);
        acc1 = fmaf(s3, fabsf(r1.w + v.w), acc1);
    }

    #pragma unroll 4
    for (int h4 = gs + 1; h4 < 32; ++h4) {     // negative-wb groups
        const float4 v  = tb[h4 << 10];
        const float4 r0 = hrA[h4];
        const float4 r1 = hrB[h4];
        acc0 -= fabsf(r0.x + v.x); acc1 -= fabsf(r1.x + v.x);
        acc0 -= fabsf(r0.y + v.y); acc1 -= fabsf(r1.y + v.y);
        acc0 -= fabsf(r0.z + v.z); acc1 -= fabsf(r1.z + v.z);
        acc0 -= fabsf(r0.w + v.w); acc1 -= fabsf(r1.w + v.w);
    }

    float sc[2];
    sc[0] = acc0 + a0v + cm;
    sc[1] = acc1 + a1v + cm;

    // ---- block-local softmax over the 1024 columns, both rows ----
    __shared__ float rmax[2][16], rsum[2][16];
    const int wid = tid >> 6, lane = tid & 63;

    #pragma unroll
    for (int n = 0; n < 2; ++n) {
        float mx = sc[n];
        #pragma unroll
        for (int off = 32; off >= 1; off >>= 1)
            mx = fmaxf(mx, __shfl_xor(mx, off, 64));
        if (lane == 0) rmax[n][wid] = mx;
    }
    __syncthreads();

    float ex[2];
    #pragma unroll
    for (int n = 0; n < 2; ++n) {
        float mx = rmax[n][0];
        #pragma unroll
        for (int k = 1; k < 16; ++k) mx = fmaxf(mx, rmax[n][k]);
        float e = expf(sc[n] - mx);
        ex[n] = e;
        float s = e;
        #pragma unroll
        for (int off = 32; off >= 1; off >>= 1) s += __shfl_xor(s, off, 64);
        if (lane == 0) rsum[n][wid] = s;
    }
    __syncthreads();

    #pragma unroll
    for (int n = 0; n < 2; ++n) {
        float s = rsum[n][0];
        #pragma unroll
        for (int k = 1; k < 16; ++k) s += rsum[n][k];
        out[(n0 + n) * NTK + tid] = ex[n] * (1.0f / s);
    }
}

extern "C" void kernel_launch(void* const* d_in, const int* in_sizes, int n_in,
                              void* d_out, int out_size, void* d_ws, size_t ws_size,
                              hipStream_t stream)
{
    const float* xr  = (const float*)d_in[0];
    const float* xt  = (const float*)d_in[1];
    // d_in[2]=edge_index, [3]=edge_attr, [4..7]=We1,be1,We2,be2 : provably dead
    const float* Wv1 = (const float*)d_in[8];
    const float* bv1 = (const float*)d_in[9];
    const float* Wv2 = (const float*)d_in[10];
    const float* bv2 = (const float*)d_in[11];
    const float* Wm1 = (const float*)d_in[12];
    const float* bm1 = (const float*)d_in[13];
    const float* Wm2 = (const float*)d_in[14];
    const float* bm2 = (const float*)d_in[15];

    float* ws     = (float*)d_ws;
    float* HTB2t4 = ws;
    float* cv     = ws + 131072;
    float* HR2    = ws + 132096;
    float* av     = ws + 197632;
    float* nPf    = ws + 198144;
    float* out    = (float*)d_out;

    hipLaunchKernelGGL(prep_kernel, dim3(256), dim3(256), 0, stream,
                       xr, xt, Wv1, bv1, Wv2, bv2, Wm1, bm1, Wm2, bm2,
                       HR2, HTB2t4, av, cv, nPf);
    hipLaunchKernelGGL(score_softmax_kernel, dim3(256), dim3(1024), 0, stream,
                       HR2, HTB2t4, av, cv, nPf, out);
}